// Round 1
// baseline (1105.262 us; speedup 1.0000x reference)
//
#include <hip/hip_runtime.h>
#include <cstdint>

#define BB 16
#define NN 25200
#define NCLS 80
#define MAXDET 300
#define MTGT 50
#define CAP 8192
#define CONF 0.8f
#define NMSTH 0.4f

// workspace byte offsets
#define WS_CNT   0
#define WS_KEYS  256
#define WS_SCORE (WS_KEYS + (size_t)BB * CAP * 8)
#define WS_IDX   (WS_SCORE + (size_t)BB * MAXDET * 4)

// output float offsets (return order: pb, ps, pl, pv, tb, ts, tl, tv)
#define O_PB 0
#define O_PS (BB * MAXDET * 4)        // 19200
#define O_PL (O_PS + BB * MAXDET)     // 24000
#define O_PV (O_PL + BB * MAXDET)     // 28800
#define O_TB (O_PV + BB * MAXDET)     // 33600
#define O_TS (O_TB + BB * MTGT * 4)   // 36800
#define O_TL (O_TS + BB * MTGT)       // 37600
#define O_TV (O_TL + BB * MTGT)       // 38400

__global__ __launch_bounds__(64) void k_zero(int* cnt) {
    if (threadIdx.x < BB) cnt[threadIdx.x] = 0;
}

// one wave per anchor: coalesced class reads + butterfly argmax (first-occurrence)
__global__ __launch_bounds__(256) void k_score(const float* __restrict__ preds,
                                               int* __restrict__ cnt,
                                               unsigned long long* __restrict__ keys) {
    int wid  = blockIdx.x * 4 + (threadIdx.x >> 6);   // global anchor id, b*NN+n
    int lane = threadIdx.x & 63;
    const float* row = preds + (size_t)wid * (5 + NCLS);

    float v = row[5 + lane];
    int   ci = lane;
    if (lane < 16) {
        float v2 = row[5 + 64 + lane];
        if (v2 > v) { v = v2; ci = lane + 64; }   // strict > keeps first occurrence
    }
    #pragma unroll
    for (int m = 32; m >= 1; m >>= 1) {
        float ov = __shfl_xor(v, m);
        int   oi = __shfl_xor(ci, m);
        if (ov > v || (ov == v && oi < ci)) { v = ov; ci = oi; }
    }
    if (lane == 0) {
        float obj   = row[4];
        float score = obj * v;                     // single f32 mul, bit-exact vs np
        if (score > CONF) {
            int b = wid / NN;
            int n = wid - b * NN;
            int pos = atomicAdd(cnt + b, 1);
            if (pos < CAP) {
                keys[(size_t)b * CAP + pos] =
                    ((unsigned long long)__float_as_uint(score) << 32) |
                    (unsigned long long)(0xFFFFFFFFu - (unsigned)n);
            }
        }
    }
}

// one block per batch: descending bitonic sort of 8192 keys in LDS
__global__ __launch_bounds__(1024) void k_sort(const int* __restrict__ cnt,
                                               const unsigned long long* __restrict__ keys,
                                               float* __restrict__ dscore,
                                               unsigned* __restrict__ didx) {
    __shared__ unsigned long long sk[CAP];
    int b = blockIdx.x;
    int tid = threadIdx.x;
    int c = cnt[b]; if (c > CAP) c = CAP;
    for (int i = tid; i < CAP; i += 1024)
        sk[i] = (i < c) ? keys[(size_t)b * CAP + i] : 0ull;

    for (unsigned k = 2; k <= CAP; k <<= 1) {
        for (unsigned j = k >> 1; j > 0; j >>= 1) {
            __syncthreads();
            #pragma unroll
            for (unsigned s = 0; s < CAP / 1024; ++s) {
                unsigned i = (s << 10) | (unsigned)tid;
                unsigned ixj = i ^ j;
                if (ixj > i) {
                    unsigned long long a = sk[i], d = sk[ixj];
                    bool desc = ((i & k) == 0);
                    if (desc ? (a < d) : (a > d)) { sk[i] = d; sk[ixj] = a; }
                }
            }
        }
    }
    __syncthreads();
    for (int q = tid; q < MAXDET; q += 1024) {
        unsigned long long key = sk[q];
        unsigned sb = (unsigned)(key >> 32);
        dscore[b * MAXDET + q] = __uint_as_float(sb);
        didx[b * MAXDET + q]   = sb ? (0xFFFFFFFFu - (unsigned)(key & 0xFFFFFFFFu)) : 0u;
    }
}

// one block per batch: gather boxes/labels, suppression matrix, greedy NMS, write outputs
__global__ __launch_bounds__(512) void k_nms(const float* __restrict__ preds,
                                             const float* __restrict__ dscore,
                                             const unsigned* __restrict__ didx,
                                             float* __restrict__ out) {
    __shared__ float    sbox[MAXDET][4];
    __shared__ float    sscore[MAXDET];
    __shared__ int      slabel[MAXDET];
    __shared__ unsigned supp[MAXDET * 10];
    __shared__ unsigned keepw[10];

    int b = blockIdx.x;
    int tid = threadIdx.x;
    int wv = tid >> 6, lane = tid & 63;

    // phase 1: per-detection box + label (wave per detection)
    for (int k = wv; k < MAXDET; k += 8) {
        float sc = dscore[b * MAXDET + k];
        int  idx = (int)didx[b * MAXDET + k];
        if (sc > 0.f) {
            const float* row = preds + ((size_t)b * NN + (size_t)idx) * (5 + NCLS);
            float v = row[5 + lane]; int ci = lane;
            if (lane < 16) { float v2 = row[5 + 64 + lane]; if (v2 > v) { v = v2; ci = lane + 64; } }
            #pragma unroll
            for (int m = 32; m >= 1; m >>= 1) {
                float ov = __shfl_xor(v, m);
                int   oi = __shfl_xor(ci, m);
                if (ov > v || (ov == v && oi < ci)) { v = ov; ci = oi; }
            }
            if (lane == 0) {
                float cx = row[0], cy = row[1], w = row[2], h = row[3];
                float x1 = cx - 0.5f * w, y1 = cy - 0.5f * h;   // 0.5*w exact -> fma-safe
                sbox[k][0] = x1; sbox[k][1] = y1; sbox[k][2] = x1 + w; sbox[k][3] = y1 + h;
                slabel[k] = ci; sscore[k] = sc;
            }
        } else if (lane == 0) {
            sbox[k][0] = 0.f; sbox[k][1] = 0.f; sbox[k][2] = 0.f; sbox[k][3] = 0.f;
            slabel[k] = -1; sscore[k] = 0.f;
        }
    }
    __syncthreads();

    for (int w = tid; w < MAXDET * 10; w += 512) supp[w] = 0u;
    if (tid < 10) {
        unsigned m = 0;
        for (int t = 0; t < 32; ++t) {
            int k = tid * 32 + t;
            if (k < MAXDET && sscore[k] > 0.f) m |= (1u << t);
        }
        keepw[tid] = m;
    }
    __syncthreads();

    // phase 2: suppression bitmask (j > i baked in); IoU op-order matches reference,
    // _rn intrinsics prevent fp-contract from flipping iou>0.4 decisions
    for (int p = tid; p < MAXDET * MAXDET; p += 512) {
        int i = p / MAXDET;
        int j = p - i * MAXDET;
        if (j > i && slabel[i] == slabel[j] && sscore[i] > 0.f && sscore[j] > 0.f) {
            float xx1 = fmaxf(sbox[i][0], sbox[j][0]);
            float yy1 = fmaxf(sbox[i][1], sbox[j][1]);
            float xx2 = fminf(sbox[i][2], sbox[j][2]);
            float yy2 = fminf(sbox[i][3], sbox[j][3]);
            float iw = fmaxf(__fsub_rn(xx2, xx1), 0.f);
            float ih = fmaxf(__fsub_rn(yy2, yy1), 0.f);
            float inter = __fmul_rn(iw, ih);
            float ai = __fmul_rn(fmaxf(__fsub_rn(sbox[i][2], sbox[i][0]), 0.f),
                                 fmaxf(__fsub_rn(sbox[i][3], sbox[i][1]), 0.f));
            float aj = __fmul_rn(fmaxf(__fsub_rn(sbox[j][2], sbox[j][0]), 0.f),
                                 fmaxf(__fsub_rn(sbox[j][3], sbox[j][1]), 0.f));
            float den = __fadd_rn(__fsub_rn(__fadd_rn(ai, aj), inter), 1e-9f);
            float iou = inter / den;
            if (iou > NMSTH) atomicOr(&supp[i * 10 + (j >> 5)], 1u << (j & 31));
        }
    }
    __syncthreads();

    // phase 3: sequential greedy pass, single wave (lockstep: lanes 0-9 own keep words)
    if (tid < 64) {
        for (int i = 0; i < MAXDET; ++i) {
            unsigned kb = keepw[i >> 5];
            if ((kb >> (i & 31)) & 1u) {
                if (tid < 10) keepw[tid] &= ~supp[i * 10 + tid];
            }
        }
    }
    __syncthreads();

    // phase 4: outputs with reference masking
    for (int k = tid; k < MAXDET; k += 512) {
        bool kp = (keepw[k >> 5] >> (k & 31)) & 1u;
        float* pb = out + O_PB + ((size_t)b * MAXDET + k) * 4;
        pb[0] = kp ? sbox[k][0] : 0.f;
        pb[1] = kp ? sbox[k][1] : 0.f;
        pb[2] = kp ? sbox[k][2] : 0.f;
        pb[3] = kp ? sbox[k][3] : 0.f;
        out[O_PS + b * MAXDET + k] = kp ? sscore[k] : 0.f;
        out[O_PL + b * MAXDET + k] = kp ? (float)slabel[k] : -1.f;
        out[O_PV + b * MAXDET + k] = kp ? 1.f : 0.f;
    }
}

__global__ __launch_bounds__(256) void k_tgt(const float* __restrict__ tt,
                                             const int* __restrict__ len,
                                             float* __restrict__ out) {
    int t = blockIdx.x * 256 + threadIdx.x;
    if (t >= BB * MTGT) return;
    int b = t / MTGT, m = t - b * MTGT;
    const float* row = tt + (size_t)t * 6;
    bool valid = m < len[b];
    float cx = row[0], cy = row[1], w = row[2], h = row[3];
    float x1 = cx - 0.5f * w, y1 = cy - 0.5f * h;
    float* tb = out + O_TB + (size_t)t * 4;
    tb[0] = valid ? x1 : 0.f;
    tb[1] = valid ? y1 : 0.f;
    tb[2] = valid ? (x1 + w) : 0.f;
    tb[3] = valid ? (y1 + h) : 0.f;
    out[O_TS + t] = valid ? row[4] : 0.f;
    out[O_TL + t] = valid ? (float)(int)row[5] : -1.f;
    out[O_TV + t] = valid ? 1.f : 0.f;
}

extern "C" void kernel_launch(void* const* d_in, const int* in_sizes, int n_in,
                              void* d_out, int out_size, void* d_ws, size_t ws_size,
                              hipStream_t stream) {
    const float* preds = (const float*)d_in[0];
    const float* tt    = (const float*)d_in[1];
    const int*   len   = (const int*)d_in[2];
    float* out = (float*)d_out;

    char* ws = (char*)d_ws;
    int* cnt                  = (int*)(ws + WS_CNT);
    unsigned long long* keys  = (unsigned long long*)(ws + WS_KEYS);
    float* dscore             = (float*)(ws + WS_SCORE);
    unsigned* didx            = (unsigned*)(ws + WS_IDX);

    k_zero<<<1, 64, 0, stream>>>(cnt);
    // B*N anchors, 1 wave each, 4 waves per 256-thread block
    k_score<<<(BB * NN) / 4, 256, 0, stream>>>(preds, cnt, keys);
    k_sort<<<BB, 1024, 0, stream>>>(cnt, keys, dscore, didx);
    k_nms<<<BB, 512, 0, stream>>>(preds, dscore, didx, out);
    k_tgt<<<(BB * MTGT + 255) / 256, 256, 0, stream>>>(tt, len, out);
}

// Round 2
// 292.507 us; speedup vs baseline: 3.7786x; 3.7786x over previous
//
#include <hip/hip_runtime.h>
#include <cstdint>

#define BB 16
#define NN 25200
#define NCLS 80
#define NF (5 + NCLS)
#define MAXDET 300
#define MTGT 50
#define CAP 8192
#define CONF 0.8f
#define NMSTH 0.4f

// workspace byte offsets
#define WS_SCORE 0
#define WS_DS ((size_t)BB * NN * 4)
#define WS_DI (WS_DS + (size_t)BB * MAXDET * 4)

// output float offsets (return order: pb, ps, pl, pv, tb, ts, tl, tv)
#define O_PB 0
#define O_PS (BB * MAXDET * 4)
#define O_PL (O_PS + BB * MAXDET)
#define O_PV (O_PL + BB * MAXDET)
#define O_TB (O_PV + BB * MAXDET)
#define O_TS (O_TB + BB * MTGT * 4)
#define O_TL (O_TS + BB * MTGT)
#define O_TV (O_TL + BB * MTGT)

// wave per anchor: coalesced reads, max-only butterfly, one 4B store, NO atomics
__global__ __launch_bounds__(1024) void k_score(const float* __restrict__ preds,
                                                float* __restrict__ scores) {
    int wid  = blockIdx.x * 16 + (threadIdx.x >> 6);  // b*NN + n
    int lane = threadIdx.x & 63;
    const float* row = preds + (size_t)wid * NF;

    float v = row[5 + lane];
    if (lane < 16) v = fmaxf(v, row[69 + lane]);
    #pragma unroll
    for (int m = 32; m >= 1; m >>= 1) v = fmaxf(v, __shfl_xor(v, m));
    if (lane == 0) scores[wid] = row[4] * v;   // single f32 mul, bit-exact vs np
}

// one block per batch: compact (wave-aggregated LDS atomic) + descending bitonic sort
__global__ __launch_bounds__(1024) void k_sort(const float* __restrict__ scores,
                                               float* __restrict__ dscore,
                                               unsigned* __restrict__ didx) {
    __shared__ unsigned long long sk[CAP];
    __shared__ int lcnt;
    int b = blockIdx.x;
    int tid = threadIdx.x;
    int lane = tid & 63;

    if (tid == 0) lcnt = 0;
    for (int i = tid; i < CAP; i += 1024) sk[i] = 0ull;
    __syncthreads();

    // compact: all lanes execute ballot/shfl every iteration (padded bound)
    for (int i = tid; i < ((NN + 1023) & ~1023); i += 1024) {
        float s = 0.f;
        bool pass = false;
        if (i < NN) { s = scores[b * NN + i]; pass = s > CONF; }
        unsigned long long mask = __ballot(pass);
        int wcnt = __popcll(mask);
        int base = 0;
        if (lane == 0 && wcnt) base = atomicAdd(&lcnt, wcnt);
        base = __shfl(base, 0);
        if (pass) {
            int pos = base + __popcll(mask & ((1ull << lane) - 1ull));
            if (pos < CAP)
                sk[pos] = ((unsigned long long)__float_as_uint(s) << 32) |
                          (unsigned long long)(0xFFFFFFFFu - (unsigned)i);
        }
    }

    // bitonic sort, descending; key low half = inverted index -> JAX top_k tie order
    for (unsigned k = 2; k <= CAP; k <<= 1) {
        for (unsigned j = k >> 1; j > 0; j >>= 1) {
            __syncthreads();
            #pragma unroll
            for (unsigned s = 0; s < CAP / 1024; ++s) {
                unsigned i = (s << 10) | (unsigned)tid;
                unsigned ixj = i ^ j;
                if (ixj > i) {
                    unsigned long long a = sk[i], d = sk[ixj];
                    bool desc = ((i & k) == 0);
                    if (desc ? (a < d) : (a > d)) { sk[i] = d; sk[ixj] = a; }
                }
            }
        }
    }
    __syncthreads();
    for (int q = tid; q < MAXDET; q += 1024) {
        unsigned long long key = sk[q];
        unsigned sb = (unsigned)(key >> 32);
        dscore[b * MAXDET + q] = __uint_as_float(sb);
        didx[b * MAXDET + q]   = sb ? (0xFFFFFFFFu - (unsigned)(key & 0xFFFFFFFFu)) : 0u;
    }
}

// one block per batch: gather boxes/labels, suppression matrix, greedy NMS, write outputs
__global__ __launch_bounds__(512) void k_nms(const float* __restrict__ preds,
                                             const float* __restrict__ dscore,
                                             const unsigned* __restrict__ didx,
                                             float* __restrict__ out) {
    __shared__ float    sbox[MAXDET][4];
    __shared__ float    sscore[MAXDET];
    __shared__ int      slabel[MAXDET];
    __shared__ unsigned supp[MAXDET * 10];
    __shared__ unsigned keepw[10];

    int b = blockIdx.x;
    int tid = threadIdx.x;
    int wv = tid >> 6, lane = tid & 63;

    // phase 1: per-detection box + label (wave per detection, first-occurrence argmax)
    for (int k = wv; k < MAXDET; k += 8) {
        float sc = dscore[b * MAXDET + k];
        int  idx = (int)didx[b * MAXDET + k];
        if (sc > 0.f) {
            const float* row = preds + ((size_t)b * NN + (size_t)idx) * NF;
            float v = row[5 + lane]; int ci = lane;
            if (lane < 16) { float v2 = row[69 + lane]; if (v2 > v) { v = v2; ci = lane + 64; } }
            #pragma unroll
            for (int m = 32; m >= 1; m >>= 1) {
                float ov = __shfl_xor(v, m);
                int   oi = __shfl_xor(ci, m);
                if (ov > v || (ov == v && oi < ci)) { v = ov; ci = oi; }
            }
            if (lane == 0) {
                float cx = row[0], cy = row[1], w = row[2], h = row[3];
                float x1 = cx - 0.5f * w, y1 = cy - 0.5f * h;   // 0.5*w exact -> fma-safe
                sbox[k][0] = x1; sbox[k][1] = y1; sbox[k][2] = x1 + w; sbox[k][3] = y1 + h;
                slabel[k] = ci; sscore[k] = sc;
            }
        } else if (lane == 0) {
            sbox[k][0] = 0.f; sbox[k][1] = 0.f; sbox[k][2] = 0.f; sbox[k][3] = 0.f;
            slabel[k] = -1; sscore[k] = 0.f;
        }
    }
    __syncthreads();

    for (int w = tid; w < MAXDET * 10; w += 512) supp[w] = 0u;
    if (tid < 10) {
        unsigned m = 0;
        for (int t = 0; t < 32; ++t) {
            int k = tid * 32 + t;
            if (k < MAXDET && sscore[k] > 0.f) m |= (1u << t);
        }
        keepw[tid] = m;
    }
    __syncthreads();

    // phase 2: suppression bitmask; IoU op-order matches reference, _rn blocks fma-contract
    for (int p = tid; p < MAXDET * MAXDET; p += 512) {
        int i = p / MAXDET;
        int j = p - i * MAXDET;
        if (j > i && slabel[i] == slabel[j] && sscore[i] > 0.f && sscore[j] > 0.f) {
            float xx1 = fmaxf(sbox[i][0], sbox[j][0]);
            float yy1 = fmaxf(sbox[i][1], sbox[j][1]);
            float xx2 = fminf(sbox[i][2], sbox[j][2]);
            float yy2 = fminf(sbox[i][3], sbox[j][3]);
            float iw = fmaxf(__fsub_rn(xx2, xx1), 0.f);
            float ih = fmaxf(__fsub_rn(yy2, yy1), 0.f);
            float inter = __fmul_rn(iw, ih);
            float ai = __fmul_rn(fmaxf(__fsub_rn(sbox[i][2], sbox[i][0]), 0.f),
                                 fmaxf(__fsub_rn(sbox[i][3], sbox[i][1]), 0.f));
            float aj = __fmul_rn(fmaxf(__fsub_rn(sbox[j][2], sbox[j][0]), 0.f),
                                 fmaxf(__fsub_rn(sbox[j][3], sbox[j][1]), 0.f));
            float den = __fadd_rn(__fsub_rn(__fadd_rn(ai, aj), inter), 1e-9f);
            float iou = inter / den;
            if (iou > NMSTH) atomicOr(&supp[i * 10 + (j >> 5)], 1u << (j & 31));
        }
    }
    __syncthreads();

    // phase 3: sequential greedy pass, single wave (lockstep: lanes 0-9 own keep words)
    if (tid < 64) {
        for (int i = 0; i < MAXDET; ++i) {
            unsigned kb = keepw[i >> 5];
            if ((kb >> (i & 31)) & 1u) {
                if (tid < 10) keepw[tid] &= ~supp[i * 10 + tid];
            }
        }
    }
    __syncthreads();

    // phase 4: outputs with reference masking
    for (int k = tid; k < MAXDET; k += 512) {
        bool kp = (keepw[k >> 5] >> (k & 31)) & 1u;
        float* pb = out + O_PB + ((size_t)b * MAXDET + k) * 4;
        pb[0] = kp ? sbox[k][0] : 0.f;
        pb[1] = kp ? sbox[k][1] : 0.f;
        pb[2] = kp ? sbox[k][2] : 0.f;
        pb[3] = kp ? sbox[k][3] : 0.f;
        out[O_PS + b * MAXDET + k] = kp ? sscore[k] : 0.f;
        out[O_PL + b * MAXDET + k] = kp ? (float)slabel[k] : -1.f;
        out[O_PV + b * MAXDET + k] = kp ? 1.f : 0.f;
    }
}

__global__ __launch_bounds__(256) void k_tgt(const float* __restrict__ tt,
                                             const int* __restrict__ len,
                                             float* __restrict__ out) {
    int t = blockIdx.x * 256 + threadIdx.x;
    if (t >= BB * MTGT) return;
    int b = t / MTGT, m = t - b * MTGT;
    const float* row = tt + (size_t)t * 6;
    bool valid = m < len[b];
    float cx = row[0], cy = row[1], w = row[2], h = row[3];
    float x1 = cx - 0.5f * w, y1 = cy - 0.5f * h;
    float* tb = out + O_TB + (size_t)t * 4;
    tb[0] = valid ? x1 : 0.f;
    tb[1] = valid ? y1 : 0.f;
    tb[2] = valid ? (x1 + w) : 0.f;
    tb[3] = valid ? (y1 + h) : 0.f;
    out[O_TS + t] = valid ? row[4] : 0.f;
    out[O_TL + t] = valid ? (float)(int)row[5] : -1.f;
    out[O_TV + t] = valid ? 1.f : 0.f;
}

extern "C" void kernel_launch(void* const* d_in, const int* in_sizes, int n_in,
                              void* d_out, int out_size, void* d_ws, size_t ws_size,
                              hipStream_t stream) {
    const float* preds = (const float*)d_in[0];
    const float* tt    = (const float*)d_in[1];
    const int*   len   = (const int*)d_in[2];
    float* out = (float*)d_out;

    char* ws = (char*)d_ws;
    float*    scores = (float*)(ws + WS_SCORE);
    float*    dscore = (float*)(ws + WS_DS);
    unsigned* didx   = (unsigned*)(ws + WS_DI);

    // B*N anchors, wave per anchor, 16 anchors per 1024-thread block
    k_score<<<(BB * NN) / 16, 1024, 0, stream>>>(preds, scores);
    k_sort<<<BB, 1024, 0, stream>>>(scores, dscore, didx);
    k_nms<<<BB, 512, 0, stream>>>(preds, dscore, didx, out);
    k_tgt<<<(BB * MTGT + 255) / 256, 256, 0, stream>>>(tt, len, out);
}

// Round 3
// 223.693 us; speedup vs baseline: 4.9410x; 1.3076x over previous
//
#include <hip/hip_runtime.h>
#include <cstdint>

#define BB 16
#define NN 25200
#define NCLS 80
#define NF (5 + NCLS)
#define MAXDET 300
#define MTGT 50
#define CAP 8192
#define CONF 0.8f
#define NMSTH 0.4f
#define WORDS 10

// workspace byte offsets
#define WS_SCORE 0
#define WS_DS   ((size_t)BB * NN * 4)
#define WS_DI   (WS_DS + (size_t)BB * MAXDET * 4)
#define WS_GBOX (WS_DI + (size_t)BB * MAXDET * 4)
#define WS_GLAB (WS_GBOX + (size_t)BB * MAXDET * 16)
#define WS_SUPP (WS_GLAB + (size_t)BB * MAXDET * 4)

// output float offsets (return order: pb, ps, pl, pv, tb, ts, tl, tv)
#define O_PB 0
#define O_PS (BB * MAXDET * 4)
#define O_PL (O_PS + BB * MAXDET)
#define O_PV (O_PL + BB * MAXDET)
#define O_TB (O_PV + BB * MAXDET)
#define O_TS (O_TB + BB * MTGT * 4)
#define O_TL (O_TS + BB * MTGT)
#define O_TV (O_TL + BB * MTGT)

// wave per anchor: coalesced reads, max-only butterfly, one 4B store, NO atomics
__global__ __launch_bounds__(1024) void k_score(const float* __restrict__ preds,
                                                float* __restrict__ scores) {
    int wid  = blockIdx.x * 16 + (threadIdx.x >> 6);  // b*NN + n
    int lane = threadIdx.x & 63;
    const float* row = preds + (size_t)wid * NF;

    float v = row[5 + lane];
    if (lane < 16) v = fmaxf(v, row[69 + lane]);
    #pragma unroll
    for (int m = 32; m >= 1; m >>= 1) v = fmaxf(v, __shfl_xor(v, m));
    if (lane == 0) scores[wid] = row[4] * v;   // single f32 mul, bit-exact vs np
}

// one block per batch: compact (wave-aggregated LDS atomic) + descending bitonic sort
__global__ __launch_bounds__(1024) void k_sort(const float* __restrict__ scores,
                                               float* __restrict__ dscore,
                                               unsigned* __restrict__ didx) {
    __shared__ unsigned long long sk[CAP];
    __shared__ int lcnt;
    int b = blockIdx.x;
    int tid = threadIdx.x;
    int lane = tid & 63;

    if (tid == 0) lcnt = 0;
    for (int i = tid; i < CAP; i += 1024) sk[i] = 0ull;
    __syncthreads();

    for (int i = tid; i < ((NN + 1023) & ~1023); i += 1024) {
        float s = 0.f;
        bool pass = false;
        if (i < NN) { s = scores[b * NN + i]; pass = s > CONF; }
        unsigned long long mask = __ballot(pass);
        int wcnt = __popcll(mask);
        int base = 0;
        if (lane == 0 && wcnt) base = atomicAdd(&lcnt, wcnt);
        base = __shfl(base, 0);
        if (pass) {
            int pos = base + __popcll(mask & ((1ull << lane) - 1ull));
            if (pos < CAP)
                sk[pos] = ((unsigned long long)__float_as_uint(s) << 32) |
                          (unsigned long long)(0xFFFFFFFFu - (unsigned)i);
        }
    }

    // bitonic sort, descending; key low half = inverted index -> JAX top_k tie order
    for (unsigned k = 2; k <= CAP; k <<= 1) {
        for (unsigned j = k >> 1; j > 0; j >>= 1) {
            __syncthreads();
            #pragma unroll
            for (unsigned s = 0; s < CAP / 1024; ++s) {
                unsigned i = (s << 10) | (unsigned)tid;
                unsigned ixj = i ^ j;
                if (ixj > i) {
                    unsigned long long a = sk[i], d = sk[ixj];
                    bool desc = ((i & k) == 0);
                    if (desc ? (a < d) : (a > d)) { sk[i] = d; sk[ixj] = a; }
                }
            }
        }
    }
    __syncthreads();
    for (int q = tid; q < MAXDET; q += 1024) {
        unsigned long long key = sk[q];
        unsigned sb = (unsigned)(key >> 32);
        dscore[b * MAXDET + q] = __uint_as_float(sb);
        didx[b * MAXDET + q]   = sb ? (0xFFFFFFFFu - (unsigned)(key & 0xFFFFFFFFu)) : 0u;
    }
}

// wave per detection: gather row, first-occurrence argmax, box -> gbox/glabel
__global__ __launch_bounds__(512) void k_gather(const float* __restrict__ preds,
                                                const float* __restrict__ dscore,
                                                const unsigned* __restrict__ didx,
                                                float* __restrict__ gbox,
                                                int* __restrict__ glabel) {
    int g    = blockIdx.x * 8 + (threadIdx.x >> 6);   // b*MAXDET + k
    int lane = threadIdx.x & 63;
    float sc = dscore[g];
    if (sc > 0.f) {
        int b = g / MAXDET;
        int idx = (int)didx[g];
        const float* row = preds + ((size_t)b * NN + (size_t)idx) * NF;
        float v = row[5 + lane]; int ci = lane;
        if (lane < 16) { float v2 = row[69 + lane]; if (v2 > v) { v = v2; ci = lane + 64; } }
        #pragma unroll
        for (int m = 32; m >= 1; m >>= 1) {
            float ov = __shfl_xor(v, m);
            int   oi = __shfl_xor(ci, m);
            if (ov > v || (ov == v && oi < ci)) { v = ov; ci = oi; }
        }
        if (lane == 0) {
            float cx = row[0], cy = row[1], w = row[2], h = row[3];
            float x1 = cx - 0.5f * w, y1 = cy - 0.5f * h;   // 0.5*w exact -> fma-safe
            float4 bx = { x1, y1, x1 + w, y1 + h };
            ((float4*)gbox)[g] = bx;
            glabel[g] = ci;
        }
    } else if (lane == 0) {
        float4 zz = { 0.f, 0.f, 0.f, 0.f };
        ((float4*)gbox)[g] = zz;
        glabel[g] = -1;
    }
}

// thread per 32-bit suppression word: 32 serial IoUs, no atomics, every word written once
__global__ __launch_bounds__(256) void k_mask(const float* __restrict__ gbox,
                                              const int* __restrict__ glabel,
                                              const float* __restrict__ dscore,
                                              unsigned* __restrict__ gsupp) {
    int T = blockIdx.x * 256 + threadIdx.x;
    if (T >= BB * MAXDET * WORDS) return;
    int g  = T / WORDS;                    // b*MAXDET + i
    int jw = T - g * WORDS;
    int b  = g / MAXDET;
    int i  = g - b * MAXDET;

    unsigned word = 0;
    int jbase = jw * 32;
    if (jbase + 31 > i) {                  // word has some j > i
        float4 bi = ((const float4*)gbox)[g];
        int   li = glabel[g];
        float si = dscore[g];
        float ai = __fmul_rn(fmaxf(__fsub_rn(bi.z, bi.x), 0.f),
                             fmaxf(__fsub_rn(bi.w, bi.y), 0.f));
        #pragma unroll 4
        for (int t = 0; t < 32; ++t) {
            int j = jbase + t;
            if (j > i && j < MAXDET) {
                int gj = b * MAXDET + j;
                if (glabel[gj] == li && si > 0.f && dscore[gj] > 0.f) {
                    float4 bj = ((const float4*)gbox)[gj];
                    float xx1 = fmaxf(bi.x, bj.x);
                    float yy1 = fmaxf(bi.y, bj.y);
                    float xx2 = fminf(bi.z, bj.z);
                    float yy2 = fminf(bi.w, bj.w);
                    float iw = fmaxf(__fsub_rn(xx2, xx1), 0.f);
                    float ih = fmaxf(__fsub_rn(yy2, yy1), 0.f);
                    float inter = __fmul_rn(iw, ih);
                    float aj = __fmul_rn(fmaxf(__fsub_rn(bj.z, bj.x), 0.f),
                                         fmaxf(__fsub_rn(bj.w, bj.y), 0.f));
                    float den = __fadd_rn(__fsub_rn(__fadd_rn(ai, aj), inter), 1e-9f);
                    float iou = inter / den;     // exact IEEE div (no fast-math)
                    if (iou > NMSTH) word |= 1u << t;
                }
            }
        }
    }
    gsupp[T] = word;
}

// one wave per batch: register-resident keep + nonzero-row summary; LDS touched only on
// actual suppressions (~15/batch). Fused output write (single wave -> no syncs needed).
__global__ __launch_bounds__(64) void k_greedy(const float* __restrict__ gbox,
                                               const int* __restrict__ glabel,
                                               const float* __restrict__ dscore,
                                               const unsigned* __restrict__ gsupp,
                                               float* __restrict__ out) {
    __shared__ unsigned ls[MAXDET * WORDS];
    int b = blockIdx.x;
    int lane = threadIdx.x;

    for (int w = lane; w < MAXDET * WORDS; w += 64)
        ls[w] = gsupp[b * MAXDET * WORDS + w];
    __syncthreads();

    // keep words + nonzero-row words distributed to lanes 0..9 via ballot
    unsigned keep = 0, nzm = 0;
    #pragma unroll
    for (int s = 0; s < 5; ++s) {
        int k = s * 64 + lane;
        bool kb = (k < MAXDET) && (dscore[b * MAXDET + k] > 0.f);
        unsigned long long m = __ballot(kb);
        if (lane == 2 * s)     keep = (unsigned)m;
        if (lane == 2 * s + 1) keep = (unsigned)(m >> 32);
        unsigned nz = 0;
        if (k < MAXDET) {
            #pragma unroll
            for (int w = 0; w < WORDS; ++w) nz |= ls[k * WORDS + w];
        }
        unsigned long long mn = __ballot(nz != 0u);
        if (lane == 2 * s)     nzm = (unsigned)mn;
        if (lane == 2 * s + 1) nzm = (unsigned)(mn >> 32);
    }

    // sequential greedy: fast path = 2 shfl + bit test (all in-register)
    for (int i = 0; i < MAXDET; ++i) {
        int idx = i >> 5;                       // uniform
        unsigned kw = __shfl(keep, idx);
        unsigned nw = __shfl(nzm, idx);
        if (((kw & nw) >> (i & 31)) & 1u) {     // keep[i] && row i nonzero (uniform)
            if (lane < WORDS) keep &= ~ls[i * WORDS + lane];
        }
    }

    // outputs with reference masking
    #pragma unroll
    for (int s = 0; s < 5; ++s) {
        int k = s * 64 + lane;
        if (k < MAXDET) {
            unsigned kw = __shfl(keep, k >> 5); // src lanes 0..9 active here
            bool kp = (kw >> (k & 31)) & 1u;
            int g = b * MAXDET + k;
            float4 bx = ((const float4*)gbox)[g];
            float4 zz = { 0.f, 0.f, 0.f, 0.f };
            ((float4*)(out + O_PB))[g] = kp ? bx : zz;
            out[O_PS + g] = kp ? dscore[g] : 0.f;
            out[O_PL + g] = kp ? (float)glabel[g] : -1.f;
            out[O_PV + g] = kp ? 1.f : 0.f;
        }
    }
}

__global__ __launch_bounds__(256) void k_tgt(const float* __restrict__ tt,
                                             const int* __restrict__ len,
                                             float* __restrict__ out) {
    int t = blockIdx.x * 256 + threadIdx.x;
    if (t >= BB * MTGT) return;
    int b = t / MTGT, m = t - b * MTGT;
    const float* row = tt + (size_t)t * 6;
    bool valid = m < len[b];
    float cx = row[0], cy = row[1], w = row[2], h = row[3];
    float x1 = cx - 0.5f * w, y1 = cy - 0.5f * h;
    float* tb = out + O_TB + (size_t)t * 4;
    tb[0] = valid ? x1 : 0.f;
    tb[1] = valid ? y1 : 0.f;
    tb[2] = valid ? (x1 + w) : 0.f;
    tb[3] = valid ? (y1 + h) : 0.f;
    out[O_TS + t] = valid ? row[4] : 0.f;
    out[O_TL + t] = valid ? (float)(int)row[5] : -1.f;
    out[O_TV + t] = valid ? 1.f : 0.f;
}

extern "C" void kernel_launch(void* const* d_in, const int* in_sizes, int n_in,
                              void* d_out, int out_size, void* d_ws, size_t ws_size,
                              hipStream_t stream) {
    const float* preds = (const float*)d_in[0];
    const float* tt    = (const float*)d_in[1];
    const int*   len   = (const int*)d_in[2];
    float* out = (float*)d_out;

    char* ws = (char*)d_ws;
    float*    scores = (float*)(ws + WS_SCORE);
    float*    dscore = (float*)(ws + WS_DS);
    unsigned* didx   = (unsigned*)(ws + WS_DI);
    float*    gbox   = (float*)(ws + WS_GBOX);
    int*      glabel = (int*)(ws + WS_GLAB);
    unsigned* gsupp  = (unsigned*)(ws + WS_SUPP);

    k_score <<<(BB * NN) / 16, 1024, 0, stream>>>(preds, scores);
    k_sort  <<<BB, 1024, 0, stream>>>(scores, dscore, didx);
    k_gather<<<(BB * MAXDET) / 8, 512, 0, stream>>>(preds, dscore, didx, gbox, glabel);
    k_mask  <<<(BB * MAXDET * WORDS + 255) / 256, 256, 0, stream>>>(gbox, glabel, dscore, gsupp);
    k_greedy<<<BB, 64, 0, stream>>>(gbox, glabel, dscore, gsupp, out);
    k_tgt   <<<(BB * MTGT + 255) / 256, 256, 0, stream>>>(tt, len, out);
}

// Round 4
// 140.545 us; speedup vs baseline: 7.8641x; 1.5916x over previous
//
#include <hip/hip_runtime.h>
#include <cstdint>

#define BB 16
#define NN 25200
#define NCLS 80
#define NF (5 + NCLS)
#define MAXDET 300
#define MTGT 50
#define CONF 0.8f
#define NMSTH 0.4f
#define WORDS 10
#define NBINS 2048
#define SBUF 2048

// workspace byte offsets
#define WS_SCORE 0
#define WS_DS   ((size_t)BB * NN * 4)
#define WS_DI   (WS_DS + (size_t)BB * MAXDET * 4)
#define WS_GBOX (WS_DI + (size_t)BB * MAXDET * 4)
#define WS_GLAB (WS_GBOX + (size_t)BB * MAXDET * 16)
#define WS_SUPP (WS_GLAB + (size_t)BB * MAXDET * 4)

// output float offsets (return order: pb, ps, pl, pv, tb, ts, tl, tv)
#define O_PB 0
#define O_PS (BB * MAXDET * 4)
#define O_PL (O_PS + BB * MAXDET)
#define O_PV (O_PL + BB * MAXDET)
#define O_TB (O_PV + BB * MAXDET)
#define O_TS (O_TB + BB * MTGT * 4)
#define O_TL (O_TS + BB * MTGT)
#define O_TV (O_TL + BB * MTGT)

// wave per anchor: coalesced reads, max-only butterfly, one 4B store, NO atomics
__global__ __launch_bounds__(1024) void k_score(const float* __restrict__ preds,
                                                float* __restrict__ scores) {
    int wid  = blockIdx.x * 16 + (threadIdx.x >> 6);  // b*NN + n
    int lane = threadIdx.x & 63;
    const float* row = preds + (size_t)wid * NF;

    float v = row[5 + lane];
    if (lane < 16) v = fmaxf(v, row[69 + lane]);
    #pragma unroll
    for (int m = 32; m >= 1; m >>= 1) v = fmaxf(v, __shfl_xor(v, m));
    if (lane == 0) scores[wid] = row[4] * v;   // single f32 mul, bit-exact vs np
}

// one block per batch: histogram top-k selection + small exact bitonic sort.
// Coarse bins only SELECT (all cut-bin ties included); the 64-bit key sort ORDERS,
// so output is bit-identical to a full sort (JAX top_k tie semantics preserved).
__global__ __launch_bounds__(1024) void k_select(const float* __restrict__ scores,
                                                 float* __restrict__ dscore,
                                                 unsigned* __restrict__ didx) {
    __shared__ int hist[NBINS];
    __shared__ unsigned long long sk[SBUF];
    __shared__ int lcnt;
    __shared__ int scut;
    int b = blockIdx.x;
    int tid = threadIdx.x;
    int lane = tid & 63;

    if (tid == 0) lcnt = 0;
    for (int i = tid; i < NBINS; i += 1024) hist[i] = 0;
    for (int i = tid; i < SBUF; i += 1024) sk[i] = 0ull;
    __syncthreads();

    // phase A: histogram of candidate score bits. scores in (0.8,1.0] share one
    // exponent region -> (u - 0x3F400000)>>12 is monotone in float order.
    for (int i = tid; i < NN; i += 1024) {
        float s = scores[b * NN + i];
        if (s > CONF) {
            unsigned u = __float_as_uint(s);
            int bin = (int)((u - 0x3F400000u) >> 12);
            bin = bin < 0 ? 0 : (bin > NBINS - 1 ? NBINS - 1 : bin);
            atomicAdd(&hist[bin], 1);
        }
    }
    __syncthreads();

    // phase B: find cut bin (largest bin with suffix-count >= 300), one wave
    if (tid < 64) {
        int sb = 0;
        #pragma unroll
        for (int k = 0; k < 32; ++k) sb += hist[tid * 32 + k];
        int cum = sb;                              // suffix sum over 64 superbins
        #pragma unroll
        for (int d = 1; d < 64; d <<= 1) {
            int o = __shfl_down(cum, d);
            if (lane + d < 64) cum += o;
        }
        unsigned long long m = __ballot(cum >= MAXDET);
        int cutbin = 0;
        if (m) {
            int cutS = 63 - __clzll(m);
            int tail = (cutS < 63) ? __shfl(cum, cutS + 1) : 0;
            int h = (lane < 32) ? hist[cutS * 32 + lane] : 0;
            int c2 = h;                            // suffix sum within superbin
            #pragma unroll
            for (int d = 1; d < 32; d <<= 1) {
                int o = __shfl_down(c2, d);
                if (lane + d < 32) c2 += o;
            }
            c2 += tail;
            unsigned long long m2 = __ballot(lane < 32 && c2 >= MAXDET);
            int cutL = 63 - __clzll(m2);           // m2 != 0 guaranteed
            cutbin = cutS * 32 + cutL;
        }
        if (lane == 0) scut = cutbin;
    }
    __syncthreads();
    int cutbin = scut;

    // phase C: compact bin >= cutbin (wave-aggregated LDS atomic)
    for (int i = tid; i < ((NN + 1023) & ~1023); i += 1024) {
        float s = 0.f; bool pass = false;
        if (i < NN) {
            s = scores[b * NN + i];
            if (s > CONF) {
                unsigned u = __float_as_uint(s);
                int bin = (int)((u - 0x3F400000u) >> 12);
                bin = bin < 0 ? 0 : (bin > NBINS - 1 ? NBINS - 1 : bin);
                pass = bin >= cutbin;
            }
        }
        unsigned long long mask = __ballot(pass);
        int wcnt = __popcll(mask);
        int base = 0;
        if (lane == 0 && wcnt) base = atomicAdd(&lcnt, wcnt);
        base = __shfl(base, 0);
        if (pass) {
            int pos = base + __popcll(mask & ((1ull << lane) - 1ull));
            if (pos < SBUF)
                sk[pos] = ((unsigned long long)__float_as_uint(s) << 32) |
                          (unsigned long long)(0xFFFFFFFFu - (unsigned)i);
        }
    }
    __syncthreads();

    // phase D: bitonic sort P in {512,1024,2048} elements, descending
    int M = lcnt; if (M > SBUF) M = SBUF;
    unsigned P = 512;
    while ((int)P < M) P <<= 1;

    for (unsigned k = 2; k <= P; k <<= 1) {
        for (unsigned j = k >> 1; j > 0; j >>= 1) {
            __syncthreads();
            for (unsigned i = tid; i < P; i += 1024) {
                unsigned ixj = i ^ j;
                if (ixj > i) {
                    unsigned long long a = sk[i], d = sk[ixj];
                    bool desc = ((i & k) == 0);
                    if (desc ? (a < d) : (a > d)) { sk[i] = d; sk[ixj] = a; }
                }
            }
        }
    }
    __syncthreads();
    for (int q = tid; q < MAXDET; q += 1024) {
        unsigned long long key = sk[q];
        unsigned sbits = (unsigned)(key >> 32);
        dscore[b * MAXDET + q] = __uint_as_float(sbits);
        didx[b * MAXDET + q]   = sbits ? (0xFFFFFFFFu - (unsigned)(key & 0xFFFFFFFFu)) : 0u;
    }
}

// wave per detection: gather row, first-occurrence argmax, box -> gbox/glabel
__global__ __launch_bounds__(512) void k_gather(const float* __restrict__ preds,
                                                const float* __restrict__ dscore,
                                                const unsigned* __restrict__ didx,
                                                float* __restrict__ gbox,
                                                int* __restrict__ glabel) {
    int g    = blockIdx.x * 8 + (threadIdx.x >> 6);   // b*MAXDET + k
    int lane = threadIdx.x & 63;
    float sc = dscore[g];
    if (sc > 0.f) {
        int b = g / MAXDET;
        int idx = (int)didx[g];
        const float* row = preds + ((size_t)b * NN + (size_t)idx) * NF;
        float v = row[5 + lane]; int ci = lane;
        if (lane < 16) { float v2 = row[69 + lane]; if (v2 > v) { v = v2; ci = lane + 64; } }
        #pragma unroll
        for (int m = 32; m >= 1; m >>= 1) {
            float ov = __shfl_xor(v, m);
            int   oi = __shfl_xor(ci, m);
            if (ov > v || (ov == v && oi < ci)) { v = ov; ci = oi; }
        }
        if (lane == 0) {
            float cx = row[0], cy = row[1], w = row[2], h = row[3];
            float x1 = cx - 0.5f * w, y1 = cy - 0.5f * h;   // 0.5*w exact -> fma-safe
            float4 bx = { x1, y1, x1 + w, y1 + h };
            ((float4*)gbox)[g] = bx;
            glabel[g] = ci;
        }
    } else if (lane == 0) {
        float4 zz = { 0.f, 0.f, 0.f, 0.f };
        ((float4*)gbox)[g] = zz;
        glabel[g] = -1;
    }
}

// thread per 32-bit suppression word: 32 serial IoUs, no atomics, every word written once
__global__ __launch_bounds__(256) void k_mask(const float* __restrict__ gbox,
                                              const int* __restrict__ glabel,
                                              const float* __restrict__ dscore,
                                              unsigned* __restrict__ gsupp) {
    int T = blockIdx.x * 256 + threadIdx.x;
    if (T >= BB * MAXDET * WORDS) return;
    int g  = T / WORDS;                    // b*MAXDET + i
    int jw = T - g * WORDS;
    int b  = g / MAXDET;
    int i  = g - b * MAXDET;

    unsigned word = 0;
    int jbase = jw * 32;
    if (jbase + 31 > i) {                  // word has some j > i
        float4 bi = ((const float4*)gbox)[g];
        int   li = glabel[g];
        float si = dscore[g];
        float ai = __fmul_rn(fmaxf(__fsub_rn(bi.z, bi.x), 0.f),
                             fmaxf(__fsub_rn(bi.w, bi.y), 0.f));
        #pragma unroll 4
        for (int t = 0; t < 32; ++t) {
            int j = jbase + t;
            if (j > i && j < MAXDET) {
                int gj = b * MAXDET + j;
                if (glabel[gj] == li && si > 0.f && dscore[gj] > 0.f) {
                    float4 bj = ((const float4*)gbox)[gj];
                    float xx1 = fmaxf(bi.x, bj.x);
                    float yy1 = fmaxf(bi.y, bj.y);
                    float xx2 = fminf(bi.z, bj.z);
                    float yy2 = fminf(bi.w, bj.w);
                    float iw = fmaxf(__fsub_rn(xx2, xx1), 0.f);
                    float ih = fmaxf(__fsub_rn(yy2, yy1), 0.f);
                    float inter = __fmul_rn(iw, ih);
                    float aj = __fmul_rn(fmaxf(__fsub_rn(bj.z, bj.x), 0.f),
                                         fmaxf(__fsub_rn(bj.w, bj.y), 0.f));
                    float den = __fadd_rn(__fsub_rn(__fadd_rn(ai, aj), inter), 1e-9f);
                    float iou = inter / den;     // exact IEEE div (no fast-math)
                    if (iou > NMSTH) word |= 1u << t;
                }
            }
        }
    }
    gsupp[T] = word;
}

// one wave per batch: register-resident keep + nonzero-row summary; LDS touched only on
// actual suppressions. Fused output write (single wave -> no syncs needed).
__global__ __launch_bounds__(64) void k_greedy(const float* __restrict__ gbox,
                                               const int* __restrict__ glabel,
                                               const float* __restrict__ dscore,
                                               const unsigned* __restrict__ gsupp,
                                               float* __restrict__ out) {
    __shared__ unsigned ls[MAXDET * WORDS];
    int b = blockIdx.x;
    int lane = threadIdx.x;

    for (int w = lane; w < MAXDET * WORDS; w += 64)
        ls[w] = gsupp[b * MAXDET * WORDS + w];
    __syncthreads();

    unsigned keep = 0, nzm = 0;
    #pragma unroll
    for (int s = 0; s < 5; ++s) {
        int k = s * 64 + lane;
        bool kb = (k < MAXDET) && (dscore[b * MAXDET + k] > 0.f);
        unsigned long long m = __ballot(kb);
        if (lane == 2 * s)     keep = (unsigned)m;
        if (lane == 2 * s + 1) keep = (unsigned)(m >> 32);
        unsigned nz = 0;
        if (k < MAXDET) {
            #pragma unroll
            for (int w = 0; w < WORDS; ++w) nz |= ls[k * WORDS + w];
        }
        unsigned long long mn = __ballot(nz != 0u);
        if (lane == 2 * s)     nzm = (unsigned)mn;
        if (lane == 2 * s + 1) nzm = (unsigned)(mn >> 32);
    }

    for (int i = 0; i < MAXDET; ++i) {
        int idx = i >> 5;                       // uniform
        unsigned kw = __shfl(keep, idx);
        unsigned nw = __shfl(nzm, idx);
        if (((kw & nw) >> (i & 31)) & 1u) {
            if (lane < WORDS) keep &= ~ls[i * WORDS + lane];
        }
    }

    #pragma unroll
    for (int s = 0; s < 5; ++s) {
        int k = s * 64 + lane;
        if (k < MAXDET) {
            unsigned kw = __shfl(keep, k >> 5);
            bool kp = (kw >> (k & 31)) & 1u;
            int g = b * MAXDET + k;
            float4 bx = ((const float4*)gbox)[g];
            float4 zz = { 0.f, 0.f, 0.f, 0.f };
            ((float4*)(out + O_PB))[g] = kp ? bx : zz;
            out[O_PS + g] = kp ? dscore[g] : 0.f;
            out[O_PL + g] = kp ? (float)glabel[g] : -1.f;
            out[O_PV + g] = kp ? 1.f : 0.f;
        }
    }
}

__global__ __launch_bounds__(256) void k_tgt(const float* __restrict__ tt,
                                             const int* __restrict__ len,
                                             float* __restrict__ out) {
    int t = blockIdx.x * 256 + threadIdx.x;
    if (t >= BB * MTGT) return;
    int b = t / MTGT, m = t - b * MTGT;
    const float* row = tt + (size_t)t * 6;
    bool valid = m < len[b];
    float cx = row[0], cy = row[1], w = row[2], h = row[3];
    float x1 = cx - 0.5f * w, y1 = cy - 0.5f * h;
    float* tb = out + O_TB + (size_t)t * 4;
    tb[0] = valid ? x1 : 0.f;
    tb[1] = valid ? y1 : 0.f;
    tb[2] = valid ? (x1 + w) : 0.f;
    tb[3] = valid ? (y1 + h) : 0.f;
    out[O_TS + t] = valid ? row[4] : 0.f;
    out[O_TL + t] = valid ? (float)(int)row[5] : -1.f;
    out[O_TV + t] = valid ? 1.f : 0.f;
}

extern "C" void kernel_launch(void* const* d_in, const int* in_sizes, int n_in,
                              void* d_out, int out_size, void* d_ws, size_t ws_size,
                              hipStream_t stream) {
    const float* preds = (const float*)d_in[0];
    const float* tt    = (const float*)d_in[1];
    const int*   len   = (const int*)d_in[2];
    float* out = (float*)d_out;

    char* ws = (char*)d_ws;
    float*    scores = (float*)(ws + WS_SCORE);
    float*    dscore = (float*)(ws + WS_DS);
    unsigned* didx   = (unsigned*)(ws + WS_DI);
    float*    gbox   = (float*)(ws + WS_GBOX);
    int*      glabel = (int*)(ws + WS_GLAB);
    unsigned* gsupp  = (unsigned*)(ws + WS_SUPP);

    k_score <<<(BB * NN) / 16, 1024, 0, stream>>>(preds, scores);
    k_select<<<BB, 1024, 0, stream>>>(scores, dscore, didx);
    k_gather<<<(BB * MAXDET) / 8, 512, 0, stream>>>(preds, dscore, didx, gbox, glabel);
    k_mask  <<<(BB * MAXDET * WORDS + 255) / 256, 256, 0, stream>>>(gbox, glabel, dscore, gsupp);
    k_greedy<<<BB, 64, 0, stream>>>(gbox, glabel, dscore, gsupp, out);
    k_tgt   <<<(BB * MTGT + 255) / 256, 256, 0, stream>>>(tt, len, out);
}

// Round 5
// 103.709 us; speedup vs baseline: 10.6574x; 1.3552x over previous
//
#include <hip/hip_runtime.h>
#include <cstdint>

#define BB 16
#define NN 25200
#define NCLS 80
#define NF (5 + NCLS)
#define MAXDET 300
#define MTGT 50
#define CONF 0.8f
#define NMSTH 0.4f
#define WORDS 10
#define NBINS 2048
#define SBUF 2048
#define APB 128                 // anchors per block in k_score

// workspace byte offsets
#define WS_SCORE 0
#define WS_DS   ((size_t)BB * NN * 4)
#define WS_DI   (WS_DS + (size_t)BB * MAXDET * 4)
#define WS_GBOX (WS_DI + (size_t)BB * MAXDET * 4)
#define WS_GLAB (WS_GBOX + (size_t)BB * MAXDET * 16)
#define WS_SUPP (WS_GLAB + (size_t)BB * MAXDET * 4)

// output float offsets (return order: pb, ps, pl, pv, tb, ts, tl, tv)
#define O_PB 0
#define O_PS (BB * MAXDET * 4)
#define O_PL (O_PS + BB * MAXDET)
#define O_PV (O_PL + BB * MAXDET)
#define O_TB (O_PV + BB * MAXDET)
#define O_TS (O_TB + BB * MTGT * 4)
#define O_TL (O_TS + BB * MTGT)
#define O_TV (O_TL + BB * MTGT)

// 256 threads stage 128 contiguous rows (43.5 KB) via aligned float4, then
// 2 threads/anchor scan 40 classes each from LDS (2 lanes/bank -> conflict-free),
// one shfl_xor(1) combine, single mul, store. Max is order-independent -> bit-exact.
__global__ __launch_bounds__(256) void k_score(const float* __restrict__ preds,
                                               float* __restrict__ scores) {
    __shared__ float st[APB * NF];          // 43520 B
    int tid  = threadIdx.x;
    int base = blockIdx.x * APB;            // first anchor of this block

    // stage: chunk start byte = blockIdx.x*APB*NF*4, APB*NF*4 % 16 == 0 -> aligned
    const float4* src = (const float4*)(preds + (size_t)base * NF);
    float4* dst = (float4*)st;
    #pragma unroll
    for (int i = 0; i < (APB * NF / 4 + 255) / 256; ++i) {
        int idx = i * 256 + tid;
        if (idx < APB * NF / 4) dst[idx] = src[idx];
    }
    __syncthreads();

    // scan: anchor a = tid>>1, half h = tid&1 covers classes [5+40h, 45+40h)
    int a = tid >> 1, h = tid & 1;
    const float* row = st + a * NF;
    const float* cls = row + 5 + h * 40;
    float m = cls[0];
    #pragma unroll
    for (int f = 1; f < 40; ++f) m = fmaxf(m, cls[f]);
    m = fmaxf(m, __shfl_xor(m, 1));
    if (h == 0) scores[base + a] = row[4] * m;   // single f32 mul, bit-exact vs np
}

// one block per batch: histogram top-k selection + small exact bitonic sort.
// Coarse bins only SELECT (all cut-bin ties included); the 64-bit key sort ORDERS,
// so output is bit-identical to a full sort (JAX top_k tie semantics preserved).
__global__ __launch_bounds__(1024) void k_select(const float* __restrict__ scores,
                                                 float* __restrict__ dscore,
                                                 unsigned* __restrict__ didx) {
    __shared__ int hist[NBINS];
    __shared__ unsigned long long sk[SBUF];
    __shared__ int lcnt;
    __shared__ int scut;
    int b = blockIdx.x;
    int tid = threadIdx.x;
    int lane = tid & 63;

    if (tid == 0) lcnt = 0;
    for (int i = tid; i < NBINS; i += 1024) hist[i] = 0;
    for (int i = tid; i < SBUF; i += 1024) sk[i] = 0ull;
    __syncthreads();

    // phase A: histogram of candidate score bits. scores in (0.8,1.0] share one
    // exponent region -> (u - 0x3F400000)>>12 is monotone in float order.
    for (int i = tid; i < NN; i += 1024) {
        float s = scores[b * NN + i];
        if (s > CONF) {
            unsigned u = __float_as_uint(s);
            int bin = (int)((u - 0x3F400000u) >> 12);
            bin = bin < 0 ? 0 : (bin > NBINS - 1 ? NBINS - 1 : bin);
            atomicAdd(&hist[bin], 1);
        }
    }
    __syncthreads();

    // phase B: find cut bin (largest bin with suffix-count >= 300), one wave
    if (tid < 64) {
        int sb = 0;
        #pragma unroll
        for (int k = 0; k < 32; ++k) sb += hist[tid * 32 + k];
        int cum = sb;                              // suffix sum over 64 superbins
        #pragma unroll
        for (int d = 1; d < 64; d <<= 1) {
            int o = __shfl_down(cum, d);
            if (lane + d < 64) cum += o;
        }
        unsigned long long m = __ballot(cum >= MAXDET);
        int cutbin = 0;
        if (m) {
            int cutS = 63 - __clzll(m);
            int tail = (cutS < 63) ? __shfl(cum, cutS + 1) : 0;
            int hh = (lane < 32) ? hist[cutS * 32 + lane] : 0;
            int c2 = hh;                           // suffix sum within superbin
            #pragma unroll
            for (int d = 1; d < 32; d <<= 1) {
                int o = __shfl_down(c2, d);
                if (lane + d < 32) c2 += o;
            }
            c2 += tail;
            unsigned long long m2 = __ballot(lane < 32 && c2 >= MAXDET);
            int cutL = 63 - __clzll(m2);           // m2 != 0 guaranteed
            cutbin = cutS * 32 + cutL;
        }
        if (lane == 0) scut = cutbin;
    }
    __syncthreads();
    int cutbin = scut;

    // phase C: compact bin >= cutbin (wave-aggregated LDS atomic)
    for (int i = tid; i < ((NN + 1023) & ~1023); i += 1024) {
        float s = 0.f; bool pass = false;
        if (i < NN) {
            s = scores[b * NN + i];
            if (s > CONF) {
                unsigned u = __float_as_uint(s);
                int bin = (int)((u - 0x3F400000u) >> 12);
                bin = bin < 0 ? 0 : (bin > NBINS - 1 ? NBINS - 1 : bin);
                pass = bin >= cutbin;
            }
        }
        unsigned long long mask = __ballot(pass);
        int wcnt = __popcll(mask);
        int bs = 0;
        if (lane == 0 && wcnt) bs = atomicAdd(&lcnt, wcnt);
        bs = __shfl(bs, 0);
        if (pass) {
            int pos = bs + __popcll(mask & ((1ull << lane) - 1ull));
            if (pos < SBUF)
                sk[pos] = ((unsigned long long)__float_as_uint(s) << 32) |
                          (unsigned long long)(0xFFFFFFFFu - (unsigned)i);
        }
    }
    __syncthreads();

    // phase D: bitonic sort P in {512,1024,2048} elements, descending
    int M = lcnt; if (M > SBUF) M = SBUF;
    unsigned P = 512;
    while ((int)P < M) P <<= 1;

    for (unsigned k = 2; k <= P; k <<= 1) {
        for (unsigned j = k >> 1; j > 0; j >>= 1) {
            __syncthreads();
            for (unsigned i = tid; i < P; i += 1024) {
                unsigned ixj = i ^ j;
                if (ixj > i) {
                    unsigned long long a = sk[i], d = sk[ixj];
                    bool desc = ((i & k) == 0);
                    if (desc ? (a < d) : (a > d)) { sk[i] = d; sk[ixj] = a; }
                }
            }
        }
    }
    __syncthreads();
    for (int q = tid; q < MAXDET; q += 1024) {
        unsigned long long key = sk[q];
        unsigned sbits = (unsigned)(key >> 32);
        dscore[b * MAXDET + q] = __uint_as_float(sbits);
        didx[b * MAXDET + q]   = sbits ? (0xFFFFFFFFu - (unsigned)(key & 0xFFFFFFFFu)) : 0u;
    }
}

// wave per detection: gather row, first-occurrence argmax, box -> gbox/glabel
__global__ __launch_bounds__(512) void k_gather(const float* __restrict__ preds,
                                                const float* __restrict__ dscore,
                                                const unsigned* __restrict__ didx,
                                                float* __restrict__ gbox,
                                                int* __restrict__ glabel) {
    int g    = blockIdx.x * 8 + (threadIdx.x >> 6);   // b*MAXDET + k
    int lane = threadIdx.x & 63;
    float sc = dscore[g];
    if (sc > 0.f) {
        int b = g / MAXDET;
        int idx = (int)didx[g];
        const float* row = preds + ((size_t)b * NN + (size_t)idx) * NF;
        float v = row[5 + lane]; int ci = lane;
        if (lane < 16) { float v2 = row[69 + lane]; if (v2 > v) { v = v2; ci = lane + 64; } }
        #pragma unroll
        for (int m = 32; m >= 1; m >>= 1) {
            float ov = __shfl_xor(v, m);
            int   oi = __shfl_xor(ci, m);
            if (ov > v || (ov == v && oi < ci)) { v = ov; ci = oi; }
        }
        if (lane == 0) {
            float cx = row[0], cy = row[1], w = row[2], h = row[3];
            float x1 = cx - 0.5f * w, y1 = cy - 0.5f * h;   // 0.5*w exact -> fma-safe
            float4 bx = { x1, y1, x1 + w, y1 + h };
            ((float4*)gbox)[g] = bx;
            glabel[g] = ci;
        }
    } else if (lane == 0) {
        float4 zz = { 0.f, 0.f, 0.f, 0.f };
        ((float4*)gbox)[g] = zz;
        glabel[g] = -1;
    }
}

// thread per 32-bit suppression word: 32 serial IoUs, no atomics, every word written once
__global__ __launch_bounds__(256) void k_mask(const float* __restrict__ gbox,
                                              const int* __restrict__ glabel,
                                              const float* __restrict__ dscore,
                                              unsigned* __restrict__ gsupp) {
    int T = blockIdx.x * 256 + threadIdx.x;
    if (T >= BB * MAXDET * WORDS) return;
    int g  = T / WORDS;                    // b*MAXDET + i
    int jw = T - g * WORDS;
    int b  = g / MAXDET;
    int i  = g - b * MAXDET;

    unsigned word = 0;
    int jbase = jw * 32;
    if (jbase + 31 > i) {                  // word has some j > i
        float4 bi = ((const float4*)gbox)[g];
        int   li = glabel[g];
        float si = dscore[g];
        float ai = __fmul_rn(fmaxf(__fsub_rn(bi.z, bi.x), 0.f),
                             fmaxf(__fsub_rn(bi.w, bi.y), 0.f));
        #pragma unroll 4
        for (int t = 0; t < 32; ++t) {
            int j = jbase + t;
            if (j > i && j < MAXDET) {
                int gj = b * MAXDET + j;
                if (glabel[gj] == li && si > 0.f && dscore[gj] > 0.f) {
                    float4 bj = ((const float4*)gbox)[gj];
                    float xx1 = fmaxf(bi.x, bj.x);
                    float yy1 = fmaxf(bi.y, bj.y);
                    float xx2 = fminf(bi.z, bj.z);
                    float yy2 = fminf(bi.w, bj.w);
                    float iw = fmaxf(__fsub_rn(xx2, xx1), 0.f);
                    float ih = fmaxf(__fsub_rn(yy2, yy1), 0.f);
                    float inter = __fmul_rn(iw, ih);
                    float aj = __fmul_rn(fmaxf(__fsub_rn(bj.z, bj.x), 0.f),
                                         fmaxf(__fsub_rn(bj.w, bj.y), 0.f));
                    float den = __fadd_rn(__fsub_rn(__fadd_rn(ai, aj), inter), 1e-9f);
                    float iou = inter / den;     // exact IEEE div (no fast-math)
                    if (iou > NMSTH) word |= 1u << t;
                }
            }
        }
    }
    gsupp[T] = word;
}

// one wave per batch: register-resident keep + nonzero-row summary; LDS touched only on
// actual suppressions. Fused output write (single wave -> no syncs needed).
__global__ __launch_bounds__(64) void k_greedy(const float* __restrict__ gbox,
                                               const int* __restrict__ glabel,
                                               const float* __restrict__ dscore,
                                               const unsigned* __restrict__ gsupp,
                                               float* __restrict__ out) {
    __shared__ unsigned ls[MAXDET * WORDS];
    int b = blockIdx.x;
    int lane = threadIdx.x;

    for (int w = lane; w < MAXDET * WORDS; w += 64)
        ls[w] = gsupp[b * MAXDET * WORDS + w];
    __syncthreads();

    unsigned keep = 0, nzm = 0;
    #pragma unroll
    for (int s = 0; s < 5; ++s) {
        int k = s * 64 + lane;
        bool kb = (k < MAXDET) && (dscore[b * MAXDET + k] > 0.f);
        unsigned long long m = __ballot(kb);
        if (lane == 2 * s)     keep = (unsigned)m;
        if (lane == 2 * s + 1) keep = (unsigned)(m >> 32);
        unsigned nz = 0;
        if (k < MAXDET) {
            #pragma unroll
            for (int w = 0; w < WORDS; ++w) nz |= ls[k * WORDS + w];
        }
        unsigned long long mn = __ballot(nz != 0u);
        if (lane == 2 * s)     nzm = (unsigned)mn;
        if (lane == 2 * s + 1) nzm = (unsigned)(mn >> 32);
    }

    for (int i = 0; i < MAXDET; ++i) {
        int idx = i >> 5;                       // uniform
        unsigned kw = __shfl(keep, idx);
        unsigned nw = __shfl(nzm, idx);
        if (((kw & nw) >> (i & 31)) & 1u) {
            if (lane < WORDS) keep &= ~ls[i * WORDS + lane];
        }
    }

    #pragma unroll
    for (int s = 0; s < 5; ++s) {
        int k = s * 64 + lane;
        if (k < MAXDET) {
            unsigned kw = __shfl(keep, k >> 5);
            bool kp = (kw >> (k & 31)) & 1u;
            int g = b * MAXDET + k;
            float4 bx = ((const float4*)gbox)[g];
            float4 zz = { 0.f, 0.f, 0.f, 0.f };
            ((float4*)(out + O_PB))[g] = kp ? bx : zz;
            out[O_PS + g] = kp ? dscore[g] : 0.f;
            out[O_PL + g] = kp ? (float)glabel[g] : -1.f;
            out[O_PV + g] = kp ? 1.f : 0.f;
        }
    }
}

__global__ __launch_bounds__(256) void k_tgt(const float* __restrict__ tt,
                                             const int* __restrict__ len,
                                             float* __restrict__ out) {
    int t = blockIdx.x * 256 + threadIdx.x;
    if (t >= BB * MTGT) return;
    int b = t / MTGT, m = t - b * MTGT;
    const float* row = tt + (size_t)t * 6;
    bool valid = m < len[b];
    float cx = row[0], cy = row[1], w = row[2], h = row[3];
    float x1 = cx - 0.5f * w, y1 = cy - 0.5f * h;
    float* tb = out + O_TB + (size_t)t * 4;
    tb[0] = valid ? x1 : 0.f;
    tb[1] = valid ? y1 : 0.f;
    tb[2] = valid ? (x1 + w) : 0.f;
    tb[3] = valid ? (y1 + h) : 0.f;
    out[O_TS + t] = valid ? row[4] : 0.f;
    out[O_TL + t] = valid ? (float)(int)row[5] : -1.f;
    out[O_TV + t] = valid ? 1.f : 0.f;
}

extern "C" void kernel_launch(void* const* d_in, const int* in_sizes, int n_in,
                              void* d_out, int out_size, void* d_ws, size_t ws_size,
                              hipStream_t stream) {
    const float* preds = (const float*)d_in[0];
    const float* tt    = (const float*)d_in[1];
    const int*   len   = (const int*)d_in[2];
    float* out = (float*)d_out;

    char* ws = (char*)d_ws;
    float*    scores = (float*)(ws + WS_SCORE);
    float*    dscore = (float*)(ws + WS_DS);
    unsigned* didx   = (unsigned*)(ws + WS_DI);
    float*    gbox   = (float*)(ws + WS_GBOX);
    int*      glabel = (int*)(ws + WS_GLAB);
    unsigned* gsupp  = (unsigned*)(ws + WS_SUPP);

    k_score <<<(BB * NN) / APB, 256, 0, stream>>>(preds, scores);
    k_select<<<BB, 1024, 0, stream>>>(scores, dscore, didx);
    k_gather<<<(BB * MAXDET) / 8, 512, 0, stream>>>(preds, dscore, didx, gbox, glabel);
    k_mask  <<<(BB * MAXDET * WORDS + 255) / 256, 256, 0, stream>>>(gbox, glabel, dscore, gsupp);
    k_greedy<<<BB, 64, 0, stream>>>(gbox, glabel, dscore, gsupp, out);
    k_tgt   <<<(BB * MTGT + 255) / 256, 256, 0, stream>>>(tt, len, out);
}

// Round 6
// 96.319 us; speedup vs baseline: 11.4750x; 1.0767x over previous
//
#include <hip/hip_runtime.h>
#include <cstdint>

#define BB 16
#define NN 25200
#define NCLS 80
#define NF (5 + NCLS)
#define MAXDET 300
#define MTGT 50
#define CONF 0.8f
#define NMSTH 0.4f
#define WORDS 10
#define NBINS 2048
#define SBUF 2048
#define APB 64                              // anchors per block in k_score
#define SCORE_BLOCKS ((BB * NN) / APB)      // 6300
#define TGT_BLOCKS ((BB * MTGT + 255) / 256)

// workspace byte offsets
#define WS_SCORE 0
#define WS_DS   ((size_t)BB * NN * 4)
#define WS_DI   (WS_DS + (size_t)BB * MAXDET * 4)
#define WS_GBOX (WS_DI + (size_t)BB * MAXDET * 4)
#define WS_GLAB (WS_GBOX + (size_t)BB * MAXDET * 16)

// output float offsets (return order: pb, ps, pl, pv, tb, ts, tl, tv)
#define O_PB 0
#define O_PS (BB * MAXDET * 4)
#define O_PL (O_PS + BB * MAXDET)
#define O_PV (O_PL + BB * MAXDET)
#define O_TB (O_PV + BB * MAXDET)
#define O_TS (O_TB + BB * MTGT * 4)
#define O_TL (O_TS + BB * MTGT)
#define O_TV (O_TL + BB * MTGT)

// 256 threads stage 64 contiguous rows (21.76 KB -> 7 blocks/CU) via aligned float4,
// then 4 threads/anchor scan 20 classes each from LDS + 2 shfl_xor hops.
// Max is order-independent -> bit-exact. Last TGT_BLOCKS blocks do the target transform.
__global__ __launch_bounds__(256) void k_score(const float* __restrict__ preds,
                                               float* __restrict__ scores,
                                               const float* __restrict__ tt,
                                               const int* __restrict__ len,
                                               float* __restrict__ out) {
    __shared__ float st[APB * NF];          // 21760 B
    int tid = threadIdx.x;

    if (blockIdx.x >= SCORE_BLOCKS) {       // fused target transform (4 blocks)
        int t = (blockIdx.x - SCORE_BLOCKS) * 256 + tid;
        if (t < BB * MTGT) {
            int b = t / MTGT, m = t - b * MTGT;
            const float* row = tt + (size_t)t * 6;
            bool valid = m < len[b];
            float cx = row[0], cy = row[1], w = row[2], h = row[3];
            float x1 = cx - 0.5f * w, y1 = cy - 0.5f * h;
            float* tb = out + O_TB + (size_t)t * 4;
            tb[0] = valid ? x1 : 0.f;
            tb[1] = valid ? y1 : 0.f;
            tb[2] = valid ? (x1 + w) : 0.f;
            tb[3] = valid ? (y1 + h) : 0.f;
            out[O_TS + t] = valid ? row[4] : 0.f;
            out[O_TL + t] = valid ? (float)(int)row[5] : -1.f;
            out[O_TV + t] = valid ? 1.f : 0.f;
        }
        return;
    }

    int base = blockIdx.x * APB;            // first anchor of this block
    // stage: chunk start byte = blockIdx.x*APB*NF*4 (=21760*blk), 16B-aligned
    const float4* src = (const float4*)(preds + (size_t)base * NF);
    float4* dst = (float4*)st;
    #pragma unroll
    for (int i = 0; i < 6; ++i) {
        int idx = i * 256 + tid;
        if (idx < APB * NF / 4) dst[idx] = src[idx];
    }
    __syncthreads();

    // scan: anchor a = tid>>2, quarter q = tid&3 covers classes [5+20q, 25+20q)
    int a = tid >> 2, q = tid & 3;
    const float* row = st + a * NF;
    const float* cls = row + 5 + q * 20;
    float m = cls[0];
    #pragma unroll
    for (int f = 1; f < 20; ++f) m = fmaxf(m, cls[f]);
    m = fmaxf(m, __shfl_xor(m, 1));
    m = fmaxf(m, __shfl_xor(m, 2));
    if (q == 0) scores[base + a] = row[4] * m;   // single f32 mul, bit-exact vs np
}

// one block per batch: histogram top-k selection + small exact bitonic sort.
// Coarse bins only SELECT (all cut-bin ties included); the 64-bit key sort ORDERS,
// so output is bit-identical to a full sort (JAX top_k tie semantics preserved).
__global__ __launch_bounds__(1024) void k_select(const float* __restrict__ scores,
                                                 float* __restrict__ dscore,
                                                 unsigned* __restrict__ didx) {
    __shared__ int hist[NBINS];
    __shared__ unsigned long long sk[SBUF];
    __shared__ int lcnt;
    __shared__ int scut;
    int b = blockIdx.x;
    int tid = threadIdx.x;
    int lane = tid & 63;

    if (tid == 0) lcnt = 0;
    for (int i = tid; i < NBINS; i += 1024) hist[i] = 0;
    for (int i = tid; i < SBUF; i += 1024) sk[i] = 0ull;
    __syncthreads();

    // phase A: histogram of candidate score bits. scores in (0.8,1.0] share one
    // exponent region -> (u - 0x3F400000)>>12 is monotone in float order.
    for (int i = tid; i < NN; i += 1024) {
        float s = scores[b * NN + i];
        if (s > CONF) {
            unsigned u = __float_as_uint(s);
            int bin = (int)((u - 0x3F400000u) >> 12);
            bin = bin < 0 ? 0 : (bin > NBINS - 1 ? NBINS - 1 : bin);
            atomicAdd(&hist[bin], 1);
        }
    }
    __syncthreads();

    // phase B: find cut bin (largest bin with suffix-count >= 300), one wave
    if (tid < 64) {
        int sb = 0;
        #pragma unroll
        for (int k = 0; k < 32; ++k) sb += hist[tid * 32 + k];
        int cum = sb;                              // suffix sum over 64 superbins
        #pragma unroll
        for (int d = 1; d < 64; d <<= 1) {
            int o = __shfl_down(cum, d);
            if (lane + d < 64) cum += o;
        }
        unsigned long long m = __ballot(cum >= MAXDET);
        int cutbin = 0;
        if (m) {
            int cutS = 63 - __clzll(m);
            int tail = (cutS < 63) ? __shfl(cum, cutS + 1) : 0;
            int hh = (lane < 32) ? hist[cutS * 32 + lane] : 0;
            int c2 = hh;                           // suffix sum within superbin
            #pragma unroll
            for (int d = 1; d < 32; d <<= 1) {
                int o = __shfl_down(c2, d);
                if (lane + d < 32) c2 += o;
            }
            c2 += tail;
            unsigned long long m2 = __ballot(lane < 32 && c2 >= MAXDET);
            int cutL = 63 - __clzll(m2);           // m2 != 0 guaranteed
            cutbin = cutS * 32 + cutL;
        }
        if (lane == 0) scut = cutbin;
    }
    __syncthreads();
    int cutbin = scut;

    // phase C: compact bin >= cutbin (wave-aggregated LDS atomic)
    for (int i = tid; i < ((NN + 1023) & ~1023); i += 1024) {
        float s = 0.f; bool pass = false;
        if (i < NN) {
            s = scores[b * NN + i];
            if (s > CONF) {
                unsigned u = __float_as_uint(s);
                int bin = (int)((u - 0x3F400000u) >> 12);
                bin = bin < 0 ? 0 : (bin > NBINS - 1 ? NBINS - 1 : bin);
                pass = bin >= cutbin;
            }
        }
        unsigned long long mask = __ballot(pass);
        int wcnt = __popcll(mask);
        int bs = 0;
        if (lane == 0 && wcnt) bs = atomicAdd(&lcnt, wcnt);
        bs = __shfl(bs, 0);
        if (pass) {
            int pos = bs + __popcll(mask & ((1ull << lane) - 1ull));
            if (pos < SBUF)
                sk[pos] = ((unsigned long long)__float_as_uint(s) << 32) |
                          (unsigned long long)(0xFFFFFFFFu - (unsigned)i);
        }
    }
    __syncthreads();

    // phase D: bitonic sort P in {512,1024,2048} elements, descending
    int M = lcnt; if (M > SBUF) M = SBUF;
    unsigned P = 512;
    while ((int)P < M) P <<= 1;

    for (unsigned k = 2; k <= P; k <<= 1) {
        for (unsigned j = k >> 1; j > 0; j >>= 1) {
            __syncthreads();
            for (unsigned i = tid; i < P; i += 1024) {
                unsigned ixj = i ^ j;
                if (ixj > i) {
                    unsigned long long a = sk[i], d = sk[ixj];
                    bool desc = ((i & k) == 0);
                    if (desc ? (a < d) : (a > d)) { sk[i] = d; sk[ixj] = a; }
                }
            }
        }
    }
    __syncthreads();
    for (int q = tid; q < MAXDET; q += 1024) {
        unsigned long long key = sk[q];
        unsigned sbits = (unsigned)(key >> 32);
        dscore[b * MAXDET + q] = __uint_as_float(sbits);
        didx[b * MAXDET + q]   = sbits ? (0xFFFFFFFFu - (unsigned)(key & 0xFFFFFFFFu)) : 0u;
    }
}

// wave per detection: gather row, first-occurrence argmax, box -> gbox/glabel
__global__ __launch_bounds__(512) void k_gather(const float* __restrict__ preds,
                                                const float* __restrict__ dscore,
                                                const unsigned* __restrict__ didx,
                                                float* __restrict__ gbox,
                                                int* __restrict__ glabel) {
    int g    = blockIdx.x * 8 + (threadIdx.x >> 6);   // b*MAXDET + k
    int lane = threadIdx.x & 63;
    float sc = dscore[g];
    if (sc > 0.f) {
        int b = g / MAXDET;
        int idx = (int)didx[g];
        const float* row = preds + ((size_t)b * NN + (size_t)idx) * NF;
        float v = row[5 + lane]; int ci = lane;
        if (lane < 16) { float v2 = row[69 + lane]; if (v2 > v) { v = v2; ci = lane + 64; } }
        #pragma unroll
        for (int m = 32; m >= 1; m >>= 1) {
            float ov = __shfl_xor(v, m);
            int   oi = __shfl_xor(ci, m);
            if (ov > v || (ov == v && oi < ci)) { v = ov; ci = oi; }
        }
        if (lane == 0) {
            float cx = row[0], cy = row[1], w = row[2], h = row[3];
            float x1 = cx - 0.5f * w, y1 = cy - 0.5f * h;   // 0.5*w exact -> fma-safe
            float4 bx = { x1, y1, x1 + w, y1 + h };
            ((float4*)gbox)[g] = bx;
            glabel[g] = ci;
        }
    } else if (lane == 0) {
        float4 zz = { 0.f, 0.f, 0.f, 0.f };
        ((float4*)gbox)[g] = zz;
        glabel[g] = -1;
    }
}

// one block per batch: boxes->LDS, suppression words into LDS (each written once,
// jw-rotated inner loop de-aliases stride-32 LDS reads), single-wave greedy, fused
// output write. IoU op-order matches reference; _rn blocks fma-contract.
__global__ __launch_bounds__(1024) void k_nms2(const float* __restrict__ gbox,
                                               const int* __restrict__ glabel,
                                               const float* __restrict__ dscore,
                                               float* __restrict__ out) {
    __shared__ float4   sbox[MAXDET];
    __shared__ int      slabel[MAXDET];
    __shared__ float    sscore[MAXDET];
    __shared__ unsigned supp[MAXDET * WORDS];
    int b = blockIdx.x;
    int tid = threadIdx.x;

    if (tid < MAXDET) {
        int g = b * MAXDET + tid;
        sbox[tid]   = ((const float4*)gbox)[g];
        slabel[tid] = glabel[g];
        sscore[tid] = dscore[g];
    }
    __syncthreads();

    // suppression bitmask: thread per 32-bit word, no atomics
    for (int T = tid; T < MAXDET * WORDS; T += 1024) {
        int i  = T / WORDS;
        int jw = T - i * WORDS;
        unsigned word = 0;
        int jbase = jw * 32;
        if (jbase + 31 > i) {
            float4 bi = sbox[i];
            int   li = slabel[i];
            float si = sscore[i];
            float ai = __fmul_rn(fmaxf(__fsub_rn(bi.z, bi.x), 0.f),
                                 fmaxf(__fsub_rn(bi.w, bi.y), 0.f));
            for (int tt = 0; tt < 32; ++tt) {
                int t = (tt + jw) & 31;       // rotation: neighbors hit different banks
                int j = jbase + t;
                if (j > i && j < MAXDET) {
                    if (slabel[j] == li && si > 0.f && sscore[j] > 0.f) {
                        float4 bj = sbox[j];
                        float xx1 = fmaxf(bi.x, bj.x);
                        float yy1 = fmaxf(bi.y, bj.y);
                        float xx2 = fminf(bi.z, bj.z);
                        float yy2 = fminf(bi.w, bj.w);
                        float iw = fmaxf(__fsub_rn(xx2, xx1), 0.f);
                        float ih = fmaxf(__fsub_rn(yy2, yy1), 0.f);
                        float inter = __fmul_rn(iw, ih);
                        float aj = __fmul_rn(fmaxf(__fsub_rn(bj.z, bj.x), 0.f),
                                             fmaxf(__fsub_rn(bj.w, bj.y), 0.f));
                        float den = __fadd_rn(__fsub_rn(__fadd_rn(ai, aj), inter), 1e-9f);
                        float iou = inter / den;     // exact IEEE div (no fast-math)
                        if (iou > NMSTH) word |= 1u << t;
                    }
                }
            }
        }
        supp[T] = word;
    }
    __syncthreads();

    // single-wave greedy: keep + nonzero-row summary in registers via ballot
    if (tid < 64) {
        int lane = tid;
        unsigned keep = 0, nzm = 0;
        #pragma unroll
        for (int s = 0; s < 5; ++s) {
            int k = s * 64 + lane;
            bool kb = (k < MAXDET) && (sscore[k] > 0.f);
            unsigned long long m = __ballot(kb);
            if (lane == 2 * s)     keep = (unsigned)m;
            if (lane == 2 * s + 1) keep = (unsigned)(m >> 32);
            unsigned nz = 0;
            if (k < MAXDET) {
                #pragma unroll
                for (int w = 0; w < WORDS; ++w) nz |= supp[k * WORDS + w];
            }
            unsigned long long mn = __ballot(nz != 0u);
            if (lane == 2 * s)     nzm = (unsigned)mn;
            if (lane == 2 * s + 1) nzm = (unsigned)(mn >> 32);
        }

        for (int i = 0; i < MAXDET; ++i) {
            int idx = i >> 5;                       // uniform
            unsigned kw = __shfl(keep, idx);
            unsigned nw = __shfl(nzm, idx);
            if (((kw & nw) >> (i & 31)) & 1u) {
                if (lane < WORDS) keep &= ~supp[i * WORDS + lane];
            }
        }

        #pragma unroll
        for (int s = 0; s < 5; ++s) {
            int k = s * 64 + lane;
            if (k < MAXDET) {
                unsigned kw = __shfl(keep, k >> 5);
                bool kp = (kw >> (k & 31)) & 1u;
                int g = b * MAXDET + k;
                float4 bx = sbox[k];
                float4 zz = { 0.f, 0.f, 0.f, 0.f };
                ((float4*)(out + O_PB))[g] = kp ? bx : zz;
                out[O_PS + g] = kp ? sscore[k] : 0.f;
                out[O_PL + g] = kp ? (float)slabel[k] : -1.f;
                out[O_PV + g] = kp ? 1.f : 0.f;
            }
        }
    }
}

extern "C" void kernel_launch(void* const* d_in, const int* in_sizes, int n_in,
                              void* d_out, int out_size, void* d_ws, size_t ws_size,
                              hipStream_t stream) {
    const float* preds = (const float*)d_in[0];
    const float* tt    = (const float*)d_in[1];
    const int*   len   = (const int*)d_in[2];
    float* out = (float*)d_out;

    char* ws = (char*)d_ws;
    float*    scores = (float*)(ws + WS_SCORE);
    float*    dscore = (float*)(ws + WS_DS);
    unsigned* didx   = (unsigned*)(ws + WS_DI);
    float*    gbox   = (float*)(ws + WS_GBOX);
    int*      glabel = (int*)(ws + WS_GLAB);

    k_score <<<SCORE_BLOCKS + TGT_BLOCKS, 256, 0, stream>>>(preds, scores, tt, len, out);
    k_select<<<BB, 1024, 0, stream>>>(scores, dscore, didx);
    k_gather<<<(BB * MAXDET) / 8, 512, 0, stream>>>(preds, dscore, didx, gbox, glabel);
    k_nms2  <<<BB, 1024, 0, stream>>>(gbox, glabel, dscore, out);
}